// Round 1
// baseline (120.966 us; speedup 1.0000x reference)
//
#include <hip/hip_runtime.h>
#include <math.h>

#define NPATCH 128
#define CH 8            // channels per patch = L / N_PATCHES
#define D 64
#define WIN 9           // max key patches ahead (diff in 1..9)
#define MAXK (WIN*CH)   // 72

__global__ __launch_bounds__(256) void signed_attn_kernel(
    const float* __restrict__ Q, const float* __restrict__ K,
    const float* __restrict__ V, const float* __restrict__ logscale,
    float* __restrict__ O, int L)
{
    __shared__ float sK[MAXK][D + 1];   // +1 pad: conflict-free column reads
    __shared__ float sV[MAXK][D + 1];
    __shared__ float sQ[CH][D];
    __shared__ float sS[CH][MAXK + 8];  // scores then A

    const int tid = threadIdx.x;
    const int bid = blockIdx.x;
    const int p   = bid & (NPATCH - 1);
    const int bh  = bid >> 7;

    const long long base  = (long long)bh * L * D;
    const long long qbase = base + (long long)(p * CH) * D;

    const int npk = min(WIN, NPATCH - 1 - p);  // valid key patches
    const int nk  = npk * CH;                  // valid keys (<= 72)

    if (nk == 0) {  // patch 127: fully masked -> A = 0 exactly
        for (int i = tid; i < CH * D; i += 256) O[qbase + i] = 0.0f;
        return;
    }

    const float scale = fminf(fmaxf(expf(logscale[0]), 1.0f), 30.0f) * 0.125f;

    // ---- stage Q (8x64 floats, float4) ----
    {
        const float4* Qg  = (const float4*)(Q + qbase);
        float4*       sQ4 = (float4*)(&sQ[0][0]);
        if (tid < CH * D / 4) sQ4[tid] = Qg[tid];
    }
    // ---- stage K,V tiles (nk x 64 floats each, float4 global loads) ----
    {
        const long long kbase = base + (long long)((p + 1) * CH) * D;
        const float4* Kg = (const float4*)(K + kbase);
        const float4* Vg = (const float4*)(V + kbase);
        const int n4 = nk * (D / 4);
        for (int i = tid; i < n4; i += 256) {
            const int k  = i >> 4;
            const int d4 = (i & 15) << 2;
            float4 kv = Kg[i];
            sK[k][d4 + 0] = kv.x; sK[k][d4 + 1] = kv.y;
            sK[k][d4 + 2] = kv.z; sK[k][d4 + 3] = kv.w;
            float4 vv = Vg[i];
            sV[k][d4 + 0] = vv.x; sV[k][d4 + 1] = vv.y;
            sV[k][d4 + 2] = vv.z; sV[k][d4 + 3] = vv.w;
        }
    }
    __syncthreads();

    // ---- scores: 8 queries x nk keys ----
    for (int s = tid; s < CH * MAXK; s += 256) {
        const int q = s / MAXK;
        const int k = s - q * MAXK;
        if (k < nk) {
            float acc = 0.0f;
#pragma unroll
            for (int d = 0; d < D; ++d) acc += sQ[q][d] * sK[k][d];
            sS[q][k] = acc;
        }
    }
    __syncthreads();

    // ---- dual softmax per query row (32 threads per row) ----
    {
        const int row  = tid >> 5;   // 0..7
        const int lane = tid & 31;
        float tv[3];
        float mp = -1e30f, mn = -1e30f;
        int cnt = 0;
        for (int k = lane; k < nk; k += 32) {
            const float t = scale * sS[row][k];
            tv[cnt++] = t;
            mp = fmaxf(mp, t);
            mn = fmaxf(mn, -t);
        }
        for (int off = 16; off > 0; off >>= 1) {
            mp = fmaxf(mp, __shfl_down(mp, off, 32));
            mn = fmaxf(mn, __shfl_down(mn, off, 32));
        }
        mp = __shfl(mp, 0, 32);
        mn = __shfl(mn, 0, 32);

        float ep[3], en[3];
        float sp = 0.0f, sn = 0.0f;
        cnt = 0;
        for (int k = lane; k < nk; k += 32) {
            const float t = tv[cnt];
            ep[cnt] = expf(t - mp);
            en[cnt] = expf(-t - mn);
            sp += ep[cnt]; sn += en[cnt];
            ++cnt;
        }
        for (int off = 16; off > 0; off >>= 1) {
            sp += __shfl_down(sp, off, 32);
            sn += __shfl_down(sn, off, 32);
        }
        sp = __shfl(sp, 0, 32);
        sn = __shfl(sn, 0, 32);
        const float rp = 1.0f / sp, rn = 1.0f / sn;
        cnt = 0;
        for (int k = lane; k < nk; k += 32) {
            sS[row][k] = ep[cnt] * rp - en[cnt] * rn;
            ++cnt;
        }
    }
    __syncthreads();

    // ---- O = A * V : 8x64 outputs ----
    for (int o = tid; o < CH * D; o += 256) {
        const int q = o >> 6;
        const int d = o & 63;
        float acc = 0.0f;
        for (int k = 0; k < nk; ++k) acc += sS[q][k] * sV[k][d];
        O[qbase + o] = acc;
    }
}

extern "C" void kernel_launch(void* const* d_in, const int* in_sizes, int n_in,
                              void* d_out, int out_size, void* d_ws, size_t ws_size,
                              hipStream_t stream) {
    const float* Q  = (const float*)d_in[0];
    const float* K  = (const float*)d_in[1];
    const float* V  = (const float*)d_in[2];
    const float* ls = (const float*)d_in[3];
    float* O = (float*)d_out;

    const int L = 1024;
    const int nBH = in_sizes[0] / (L * D);  // B*H = 32
    dim3 grid(nBH * NPATCH);                // 4096 blocks
    signed_attn_kernel<<<grid, 256, 0, stream>>>(Q, K, V, ls, O, L);
}